// Round 3
// baseline (406.475 us; speedup 1.0000x reference)
//
#include <hip/hip_runtime.h>
#include <hip/hip_bf16.h>

#define NUM_HEADS 32
#define NUM_KV 8
#define GQA 4
#define HD 128
#define BM 32          // q rows per attn block
#define BN 64          // keys per k-tile
#define MAXS 1024
#define QTMAX (MAXS / BM)   // 32
#define KSTR 136            // Kt row stride (u16)
#define VSTR 72             // Vt row stride (u16)

typedef unsigned short u16;
typedef unsigned int u32;
typedef __attribute__((ext_vector_type(8))) short bf16x8;
typedef __attribute__((ext_vector_type(4))) short bf16x4;
typedef __attribute__((ext_vector_type(4))) float f32x4;
typedef __attribute__((ext_vector_type(4))) float f4v;

__device__ __forceinline__ u16 f2bf(float f) {
    __hip_bfloat16 h = __float2bfloat16(f);
    return __builtin_bit_cast(u16, h);
}

// ---------------- inverse slot map (d_ws) ----------------

__global__ void inv_init(int* __restrict__ inv, int n) {
    int i = blockIdx.x * blockDim.x + threadIdx.x;
    for (; i < n; i += gridDim.x * blockDim.x) inv[i] = -1;
}

__global__ void inv_scatter(const int* __restrict__ slot, int* __restrict__ inv,
                            int total, int nslots) {
    int i = blockIdx.x * blockDim.x + threadIdx.x;
    if (i < total) {
        int s = slot[i];
        if (s >= 0 && s < nslots) inv[s] = i;
    }
}

// ---------------- fused: cache write + flash attention ----------------
// S^T = K*Q^T so P^T's C-layout (key=quad*4+r, qrow=lane&15) is directly a
// valid B fragment for mfma_f32_16x16x16_bf16 -> no P transpose at all.

__global__ __launch_bounds__(256, 3) void fused_kernel(
    const float* __restrict__ q, const float* __restrict__ kk, const float* __restrict__ vv,
    const float* __restrict__ kci, const float* __restrict__ vci,
    const int* __restrict__ inv,
    const int* __restrict__ cu_q, const int* __restrict__ cu_k,
    float* __restrict__ out, float* __restrict__ kco, float* __restrict__ vco,
    int nseq, int nslots, int W, int nattn)
{
    __shared__ __align__(16) u16 Kt[BN * KSTR];        // [key][dim] bf16
    __shared__ __align__(16) u16 Vt[HD * VSTR];        // [dim][key] bf16 (transposed)

    const int bid = blockIdx.x;
    const int tid = threadIdx.x;

    int u, wid = -1;
    if (bid < 3 * W) {
        int t3 = bid / 3, r3 = bid - 3 * t3;
        if (r3 == 2) { wid = t3; u = -1; }
        else u = t3 * 2 + r3;
    } else {
        u = 2 * W + (bid - 3 * W);
    }

    // ---------------- copy worker path ----------------
    if (wid >= 0) {
        const f4v* k4   = (const f4v*)kk;
        const f4v* v4   = (const f4v*)vv;
        const f4v* kci4 = (const f4v*)kci;
        const f4v* vci4 = (const f4v*)vci;
        f4v* kco4 = (f4v*)kco;
        f4v* vco4 = (f4v*)vco;
        for (int s = wid; s < nslots; s += W) {
            int t = inv[s];                         // block-uniform
            size_t so = (size_t)s * 256 + tid;
            f4v kv, vvv;
            if (t >= 0) {
                size_t to = (size_t)t * 256 + tid;
                kv  = k4[to];
                vvv = v4[to];
            } else {
                kv  = __builtin_nontemporal_load(&kci4[so]);
                vvv = __builtin_nontemporal_load(&vci4[so]);
            }
            __builtin_nontemporal_store(kv,  &kco4[so]);
            __builtin_nontemporal_store(vvv, &vco4[so]);
        }
        return;
    }

    // ---------------- attention path ----------------
    if (u >= nattn) return;
    const int per = nseq * NUM_KV;
    const int qt = QTMAX - 1 - u / per;
    const int inner = u % per;
    const int kvh = inner % NUM_KV;
    const int b = inner / NUM_KV;

    const int q0 = cu_q[b];
    const int Lq = cu_q[b + 1] - q0;
    const int k0 = cu_k[b];
    const int Lk = cu_k[b + 1] - k0;
    const int qbase = qt * BM;
    if (qbase >= Lq) return;

    const int wave = tid >> 6;
    const int lane = tid & 63;
    const int c = lane & 15;
    const int quad = lane >> 4;
    const int h = kvh * GQA + wave;

    // ---- Q fragments (B operand; scale * log2e folded in) ----
    const float qs = 0.08838834764831845f * 1.44269504088896340f;
    bf16x8 qf[2][4];
#pragma unroll
    for (int rt = 0; rt < 2; ++rt) {
        int row = qbase + rt * 16 + c;
        int tok = q0 + (row < Lq ? row : Lq - 1);
        const float* qp = q + ((size_t)tok * NUM_HEADS + h) * HD + quad * 8;
#pragma unroll
        for (int kc = 0; kc < 4; ++kc) {
            float4 x = *(const float4*)(qp + kc * 32);
            float4 y = *(const float4*)(qp + kc * 32 + 4);
            union { bf16x8 v; u16 s[8]; } uu;
            uu.s[0] = f2bf(x.x * qs); uu.s[1] = f2bf(x.y * qs);
            uu.s[2] = f2bf(x.z * qs); uu.s[3] = f2bf(x.w * qs);
            uu.s[4] = f2bf(y.x * qs); uu.s[5] = f2bf(y.y * qs);
            uu.s[6] = f2bf(y.z * qs); uu.s[7] = f2bf(y.w * qs);
            qf[rt][kc] = uu.v;
        }
    }

    // O^T accumulators: lane holds qrow = c; dims = nt2*16 + quad*4 + r
    f32x4 Oacc[2][8];
    float m_i[2], l_i[2];
#pragma unroll
    for (int rt = 0; rt < 2; ++rt) {
        m_i[rt] = -3.0e38f;
        l_i[rt] = 0.0f;
#pragma unroll
        for (int nt = 0; nt < 8; ++nt) Oacc[rt][nt] = (f32x4)(0.0f);
    }

    const int kmax = min(qbase + BM, Lk);
    const int ntile = (kmax + BN - 1) / BN;

    // staging decomposition (256 threads)
    const int kst_key = tid >> 2;      // 0..63
    const int kst_g   = tid & 3;       // dim-group of 32 dims
    const int vp2     = tid >> 3;      // 0..31 key-pair
    const int vdg     = tid & 7;       // dim-group of 16 dims
    const int vgran   = vp2 >> 2;      // key granule 0..7
    const int vko     = (vp2 & 3) * 2; // u16 offset within granule

    for (int it = 0; it < ntile; ++it) {
        const int kbase = it * BN;
        __syncthreads();
        // ---- stage K tile [key][dim] ----
        {
            int kp = kbase + kst_key;
            int tok = k0 + (kp < Lk ? kp : Lk - 1);
            const float* kg = kk + ((size_t)tok * NUM_KV + kvh) * HD + kst_g * 32;
            u16* krow = &Kt[kst_key * KSTR];
#pragma unroll
            for (int j = 0; j < 4; ++j) {
                float4 x = ((const float4*)kg)[2 * j];
                float4 y = ((const float4*)kg)[2 * j + 1];
                uint4 p;
                p.x = f2bf(x.x) | ((u32)f2bf(x.y) << 16);
                p.y = f2bf(x.z) | ((u32)f2bf(x.w) << 16);
                p.z = f2bf(y.x) | ((u32)f2bf(y.y) << 16);
                p.w = f2bf(y.z) | ((u32)f2bf(y.w) << 16);
                *(uint4*)&krow[(kst_g * 4 + j) * 8] = p;
            }
        }
        // ---- stage V transposed [dim][key], granule pos = (kgran + dim>>4)&7 ----
        {
            int key0 = kbase + 2 * vp2;
            int tok0 = k0 + (key0     < Lk ? key0     : Lk - 1);
            int tok1 = k0 + (key0 + 1 < Lk ? key0 + 1 : Lk - 1);
            const float* va = vv + ((size_t)tok0 * NUM_KV + kvh) * HD + vdg * 16;
            const float* vb = vv + ((size_t)tok1 * NUM_KV + kvh) * HD + vdg * 16;
            int pos = ((vgran + vdg) & 7) * 8 + vko;
#pragma unroll
            for (int i4 = 0; i4 < 4; ++i4) {
                float4 a = ((const float4*)va)[i4];
                float4 bb = ((const float4*)vb)[i4];
                int d0 = vdg * 16 + i4 * 4;
                *(u32*)&Vt[(d0 + 0) * VSTR + pos] = f2bf(a.x) | ((u32)f2bf(bb.x) << 16);
                *(u32*)&Vt[(d0 + 1) * VSTR + pos] = f2bf(a.y) | ((u32)f2bf(bb.y) << 16);
                *(u32*)&Vt[(d0 + 2) * VSTR + pos] = f2bf(a.z) | ((u32)f2bf(bb.z) << 16);
                *(u32*)&Vt[(d0 + 3) * VSTR + pos] = f2bf(a.w) | ((u32)f2bf(bb.w) << 16);
            }
        }
        __syncthreads();

        // ---- S^T = K Q^T : lane holds qrow=c; key = kbase + nt*16 + quad*4 + r ----
        f32x4 S[2][4];
#pragma unroll
        for (int rt = 0; rt < 2; ++rt)
#pragma unroll
            for (int nt = 0; nt < 4; ++nt) S[rt][nt] = (f32x4)(0.0f);
#pragma unroll
        for (int nt = 0; nt < 4; ++nt) {
            int key = nt * 16 + c;
#pragma unroll
            for (int kc = 0; kc < 4; ++kc) {
                bf16x8 kf = *(const bf16x8*)&Kt[key * KSTR + (kc * 4 + quad) * 8];
                S[0][nt] = __builtin_amdgcn_mfma_f32_16x16x32_bf16(kf, qf[0][kc], S[0][nt], 0, 0, 0);
                S[1][nt] = __builtin_amdgcn_mfma_f32_16x16x32_bf16(kf, qf[1][kc], S[1][nt], 0, 0, 0);
            }
        }

        // ---- online softmax (per-lane scalar m/l); pk = B fragments for PV ----
        bf16x4 pk[2][4];
#pragma unroll
        for (int rt = 0; rt < 2; ++rt) {
            int rtb = qbase + rt * 16;
            int qrow_abs = rtb + c;
            bool notfull = !((kbase + BN <= rtb + 1) && (kbase + BN <= Lk));
            if (notfull) {
#pragma unroll
                for (int nt = 0; nt < 4; ++nt) {
                    int kb4 = kbase + nt * 16 + quad * 4;
#pragma unroll
                    for (int r = 0; r < 4; ++r) {
                        int key = kb4 + r;
                        if (!(key <= qrow_abs && key < Lk)) S[rt][nt][r] = -3.0e38f;
                    }
                }
            }
            float rm = -3.0e38f;
#pragma unroll
            for (int nt = 0; nt < 4; ++nt)
#pragma unroll
                for (int r = 0; r < 4; ++r) rm = fmaxf(rm, S[rt][nt][r]);
            rm = fmaxf(rm, __shfl_xor(rm, 16));
            rm = fmaxf(rm, __shfl_xor(rm, 32));
            float mn = fmaxf(m_i[rt], rm);
            float al = exp2f(m_i[rt] - mn);
            m_i[rt] = mn;
            float rs = 0.0f;
#pragma unroll
            for (int nt = 0; nt < 4; ++nt) {
#pragma unroll
                for (int r = 0; r < 4; ++r) {
                    float p = exp2f(S[rt][nt][r] - mn);
                    S[rt][nt][r] = p;
                    rs += p;
                }
                union { bf16x4 v; u16 s[4]; } pu;
                pu.s[0] = f2bf(S[rt][nt][0]); pu.s[1] = f2bf(S[rt][nt][1]);
                pu.s[2] = f2bf(S[rt][nt][2]); pu.s[3] = f2bf(S[rt][nt][3]);
                pk[rt][nt] = pu.v;
            }
            rs += __shfl_xor(rs, 16);
            rs += __shfl_xor(rs, 32);
            l_i[rt] = l_i[rt] * al + rs;
#pragma unroll
            for (int nt = 0; nt < 8; ++nt)
#pragma unroll
                for (int r = 0; r < 4; ++r)
                    Oacc[rt][nt][r] *= al;
        }

        // ---- O^T += V^T P^T (A = V^T from LDS, B = pk in-register) ----
#pragma unroll
        for (int nt2 = 0; nt2 < 8; ++nt2) {
            int dim = nt2 * 16 + c;
#pragma unroll
            for (int nt = 0; nt < 4; ++nt) {
                int g = nt * 2 + (quad >> 1);
                bf16x4 vf = *(const bf16x4*)&Vt[dim * VSTR + ((g + nt2) & 7) * 8 + (quad & 1) * 4];
                Oacc[0][nt2] = __builtin_amdgcn_mfma_f32_16x16x16bf16_1k(vf, pk[0][nt], Oacc[0][nt2], 0, 0, 0);
                Oacc[1][nt2] = __builtin_amdgcn_mfma_f32_16x16x16bf16_1k(vf, pk[1][nt], Oacc[1][nt2], 0, 0, 0);
            }
        }
    }

    // ---- epilogue: normalize and store (dims quad*4+r contiguous -> float4) ----
#pragma unroll
    for (int rt = 0; rt < 2; ++rt) {
        float li = 1.0f / l_i[rt];
        int qrow = qbase + rt * 16 + c;
        if (qrow < Lq) {
            float* op = out + ((size_t)(q0 + qrow) * NUM_HEADS + h) * HD + quad * 4;
#pragma unroll
            for (int nt2 = 0; nt2 < 8; ++nt2) {
                f32x4 o = Oacc[rt][nt2];
                float4 w = make_float4(o[0] * li, o[1] * li, o[2] * li, o[3] * li);
                *(float4*)(op + nt2 * 16) = w;
            }
        }
    }
}

extern "C" void kernel_launch(void* const* d_in, const int* in_sizes, int n_in,
                              void* d_out, int out_size, void* d_ws, size_t ws_size,
                              hipStream_t stream) {
    const float* q   = (const float*)d_in[0];
    const float* k   = (const float*)d_in[1];
    const float* v   = (const float*)d_in[2];
    const float* kci = (const float*)d_in[3];
    const float* vci = (const float*)d_in[4];
    const int* slot  = (const int*)d_in[5];
    const int* cuq   = (const int*)d_in[6];
    const int* cuk   = (const int*)d_in[7];

    int total  = in_sizes[0] / (NUM_HEADS * HD);
    int nslots = in_sizes[3] / (NUM_KV * HD);
    int nseq   = in_sizes[6] - 1;

    float* out = (float*)d_out;
    float* kco = out + (size_t)total * NUM_HEADS * HD;
    float* vco = kco + (size_t)nslots * NUM_KV * HD;

    int* inv = (int*)d_ws;
    int nattn = QTMAX * nseq * NUM_KV;
    int W = nattn / 2;
    if (W > 512) W = 512;

    inv_init<<<64, 256, 0, stream>>>(inv, nslots);
    inv_scatter<<<(total + 255) / 256, 256, 0, stream>>>(slot, inv, total, nslots);
    fused_kernel<<<nattn + W, 256, 0, stream>>>(q, k, v, kci, vci, inv, cuq, cuk,
                                                out, kco, vco, nseq, nslots, W, nattn);
}